// Round 20
// baseline (76.470 us; speedup 1.0000x reference)
//
#include <hip/hip_runtime.h>

typedef __attribute__((ext_vector_type(8))) _Float16 f16x8;
typedef __attribute__((ext_vector_type(4))) float f32x4;

#define HSTR 264   // fp16 per A/C row (528B): 16B-aligned, staggered banks

// ---- prep: g-weights fragment-contiguous fp16; f-weights transposed fp16 ----
__global__ __launch_bounds__(256) void prep_kernel(
    const float* __restrict__ gW0, const float* __restrict__ gW1,
    const float* __restrict__ fW0, const float* __restrict__ fW1,
    _Float16* __restrict__ W0c, _Float16* __restrict__ W1c,
    _Float16* __restrict__ fW0c, _Float16* __restrict__ fW1c)
{
  const int t = blockIdx.x * 256 + threadIdx.x;  // 0..65535
  {
    const int c = t >> 7, k = t & 127;           // c in [0,512), k in [0,128)
    const int dst = ((k >> 5) * 32 + (c >> 4)) * 512 +
                    (((k >> 3) & 3) * 16 + (c & 15)) * 8 + (k & 7);
    const int src = (k + ((c >= 256) ? 128 : 0)) * 256 + (c & 255);
    W0c[dst] = (_Float16)gW0[src];
  }
  {
    const int n = t >> 8, k = t & 255;           // n in [0,256), k in [0,256)
    const int dst = ((k >> 5) * 16 + (n >> 4)) * 512 +
                    (((k >> 3) & 3) * 16 + (n & 15)) * 8 + (k & 7);
    W1c[dst] = (_Float16)gW1[k * 256 + n];
  }
  {
    // f-MLP weights: row-per-output-col layout fWc[n][k] so each fmlp thread
    // streams its OWN contiguous 512B row (32 independent 16B loads).
    const int n = t >> 8, k = t & 255;
    fW0c[n * 256 + k] = (_Float16)fW0[k * 256 + n];
    fW1c[n * 256 + k] = (_Float16)fW1[k * 256 + n];
  }
}

// ---- main: EXACT r15 core (converged at 57.4us over r13/r15/r19 variants) ----
// producer/consumer u via lane-linear LDS, 64 AGPR-pinned W1 fragments,
// builtin MFMAs, 8 waves, (512,4) -> 2 blocks/CU, 4 waves/SIMD.
__global__ __launch_bounds__(512, 4) void pair_kernel(
    const float* __restrict__ state,
    const _Float16* __restrict__ W0c, const float* __restrict__ gb0,
    const _Float16* __restrict__ W1c, const float* __restrict__ gb1,
    float* __restrict__ pooled)
{
  const int b   = blockIdx.x;
  const int tid = threadIdx.x;
  const int w   = tid >> 6;   // wave 0..7
  const int l   = tid & 63;
  const int lr  = l & 15;
  const int lg  = l >> 4;

  __shared__ __align__(16) char smem[8448 + 32768];
  _Float16* A_lds = (_Float16*)smem;
  char*     ubuf  = smem + 8448;
  _Float16* C_st  = (_Float16*)ubuf;   // staging overlay, dead after creg capture

  const float* stb = state + (size_t)b * 2048;

  // ---------------- Phase 2: [A|C] = state[16x128] @ W0 (fp16 MFMA) ----------------
  f16x8 sfrag[4];
  #pragma unroll
  for (int kk = 0; kk < 4; ++kk) {
    const float* sp = stb + lr * 128 + kk * 32 + lg * 8;
    f32x4 s0 = *(const f32x4*)sp;
    f32x4 s1 = *(const f32x4*)(sp + 4);
    f16x8 f;
    f[0] = (_Float16)s0[0]; f[1] = (_Float16)s0[1];
    f[2] = (_Float16)s0[2]; f[3] = (_Float16)s0[3];
    f[4] = (_Float16)s1[0]; f[5] = (_Float16)s1[1];
    f[6] = (_Float16)s1[2]; f[7] = (_Float16)s1[3];
    sfrag[kk] = f;
  }

  const f32x4 z4 = {0.f, 0.f, 0.f, 0.f};
  f32x4 acc2[4];
  #pragma unroll
  for (int nt = 0; nt < 4; ++nt) acc2[nt] = z4;

  #pragma unroll
  for (int nt = 0; nt < 4; ++nt) {
    #pragma unroll
    for (int kk = 0; kk < 4; ++kk) {
      f16x8 bf = *(const f16x8*)(W0c + (size_t)((kk * 32 + 4 * w + nt) * 512 + l * 8));
      acc2[nt] = __builtin_amdgcn_mfma_f32_16x16x32_f16(sfrag[kk], bf, acc2[nt], 0, 0, 0);
    }
  }

  // W1 fragments for this wave's N-cols [32w,32w+32): AGPR-pinned, no remat
  f16x8 bw[2][8];
  #pragma unroll
  for (int nt = 0; nt < 2; ++nt) {
    #pragma unroll
    for (int kk = 0; kk < 8; ++kk) {
      bw[nt][kk] = *(const f16x8*)(W1c + (size_t)((kk * 16 + 2 * w + nt) * 512 + l * 8));
      asm volatile("" : "+a"(bw[nt][kk]));   // park in AGPR (64 total: proven safe)
    }
  }
  float gb1v[2];
  gb1v[0] = gb1[32 * w + lr];
  gb1v[1] = gb1[32 * w + 16 + lr];

  // store phase-2 results as fp16 (C/D layout: col=lr, row=lg*4+r); fold gb0
  #pragma unroll
  for (int nt = 0; nt < 4; ++nt) {
    const int col = 64 * w + 16 * nt + lr;
    #pragma unroll
    for (int r = 0; r < 4; ++r) {
      const int row = lg * 4 + r;
      const float v = acc2[nt][r];
      if (col < 256) A_lds[row * HSTR + col]       = (_Float16)(v + gb0[col]);
      else           C_st[row * HSTR + col - 256]  = (_Float16)v;
    }
  }
  __syncthreads();

  // creg: only this wave's produce kk-half (w&1): kk = kh..kh+3 -> 16 VGPR
  const int kh = (w & 1) * 4;
  f16x8 creg[4];
  #pragma unroll
  for (int kq = 0; kq < 4; ++kq)
    creg[kq] = *(const f16x8*)&C_st[lr * HSTR + (kh + kq) * 32 + lg * 8];
  __syncthreads();   // C_st dead; ubuf writable

  const f16x8 zh = {(_Float16)0, (_Float16)0, (_Float16)0, (_Float16)0,
                    (_Float16)0, (_Float16)0, (_Float16)0, (_Float16)0};

  const int tc = w >> 1;             // tile this wave co-produces
  float pp0 = 0.f, pp1 = 0.f;

  #pragma unroll 1
  for (int g = 0; g < 4; ++g) {
    // ---- produce: wave w builds tile i = 4g + tc, kk in [kh, kh+4) ----
    {
      const int ip = 4 * g + tc;
      char* tb = ubuf + tc * 8192;
      #pragma unroll
      for (int kq = 0; kq < 4; ++kq) {
        const int kk = kh + kq;
        f16x8 av = *(const f16x8*)&A_lds[ip * HSTR + kk * 32 + lg * 8];  // bcast
        f16x8 u = __builtin_elementwise_max(av + creg[kq], zh);
        *(f16x8*)(tb + kk * 1024 + l * 16) = u;
      }
    }
    __syncthreads();   // all 4 tiles of this round ready

    // ---- consume: all 4 tiles, ds_read_b128 (linear sweep) -> builtin MFMA ----
    #pragma unroll
    for (int t = 0; t < 4; ++t) {
      const char* tb = ubuf + t * 8192;
      f32x4 a0 = z4, a1 = z4;
      #pragma unroll
      for (int kk = 0; kk < 8; ++kk) {
        f16x8 uf = *(const f16x8*)(tb + kk * 1024 + l * 16);
        a0 = __builtin_amdgcn_mfma_f32_16x16x32_f16(uf, bw[0][kk], a0, 0, 0, 0);
        a1 = __builtin_amdgcn_mfma_f32_16x16x32_f16(uf, bw[1][kk], a1, 0, 0, 0);
      }
      const int i = 4 * g + t;
      #pragma unroll
      for (int r = 0; r < 4; ++r) {
        const int row = lg * 4 + r;       // = j
        const float v0 = fmaxf(a0[r] + gb1v[0], 0.f);
        const float v1 = fmaxf(a1[r] + gb1v[1], 0.f);
        pp0 += (row == i) ? 0.f : v0;     // mask the (i,i) filler pair
        pp1 += (row == i) ? 0.f : v1;
      }
    }
    __syncthreads();   // tiles consumed; next round may overwrite ubuf
  }

  // reduce the 4 lane-groups (disjoint j subsets, same col), write pooled
  {
    float v = pp0;
    v += __shfl_xor(v, 16);
    v += __shfl_xor(v, 32);
    if (lg == 0) pooled[(size_t)b * 256 + 32 * w + lr] = v;
  }
  {
    float v = pp1;
    v += __shfl_xor(v, 16);
    v += __shfl_xor(v, 32);
    if (lg == 0) pooled[(size_t)b * 256 + 32 * w + 16 + lr] = v;
  }
}

// ---- f-MLP: 256 blocks x 4 batches; per-thread CONTIGUOUS fp16 weight rows ----
// r10 evidence: the old k-major GEMV was L2-LATENCY-bound (dependent 1KB
// row-broadcast loads, ~1 wave/SIMD -> 57us at 128 blocks). Now thread n
// streams fWc[n][0..256) as 32 independent 16B loads (unroll 8 -> 8 in
// flight); pooled/h1 broadcast from LDS (same-address = conflict-free).
__global__ __launch_bounds__(256) void fmlp_kernel(
    const float* __restrict__ pooled,
    const _Float16* __restrict__ fW0c, const float* __restrict__ fb0,
    const _Float16* __restrict__ fW1c, const float* __restrict__ fb1,
    float* __restrict__ out)
{
  const int tid = threadIdx.x;
  const size_t b0 = (size_t)blockIdx.x * 4;
  __shared__ float pl[4][256];
  __shared__ float h1[4][256];

  #pragma unroll
  for (int q = 0; q < 4; ++q)
    pl[q][tid] = pooled[(b0 + q) * 256 + tid];
  __syncthreads();

  {
    float acc[4] = {0.f, 0.f, 0.f, 0.f};
    const _Float16* wr = fW0c + (size_t)tid * 256;
    #pragma unroll 8
    for (int it = 0; it < 32; ++it) {
      f16x8 w8 = *(const f16x8*)(wr + it * 8);
      #pragma unroll
      for (int e = 0; e < 8; ++e) {
        const float wf = (float)w8[e];
        const int k = it * 8 + e;
        #pragma unroll
        for (int q = 0; q < 4; ++q) acc[q] = fmaf(pl[q][k], wf, acc[q]);
      }
    }
    #pragma unroll
    for (int q = 0; q < 4; ++q) h1[q][tid] = fmaxf(acc[q] + fb0[tid], 0.f);
  }
  __syncthreads();
  {
    float acc[4] = {0.f, 0.f, 0.f, 0.f};
    const _Float16* wr = fW1c + (size_t)tid * 256;
    #pragma unroll 8
    for (int it = 0; it < 32; ++it) {
      f16x8 w8 = *(const f16x8*)(wr + it * 8);
      #pragma unroll
      for (int e = 0; e < 8; ++e) {
        const float wf = (float)w8[e];
        const int k = it * 8 + e;
        #pragma unroll
        for (int q = 0; q < 4; ++q) acc[q] = fmaf(h1[q][k], wf, acc[q]);
      }
    }
    #pragma unroll
    for (int q = 0; q < 4; ++q)
      out[(b0 + q) * 256 + tid] = fmaxf(acc[q] + fb1[tid], 0.f);
  }
}

extern "C" void kernel_launch(void* const* d_in, const int* in_sizes, int n_in,
                              void* d_out, int out_size, void* d_ws, size_t ws_size,
                              hipStream_t stream) {
  const float* state = (const float*)d_in[0];
  const float* gW0   = (const float*)d_in[1];
  const float* gb0   = (const float*)d_in[2];
  const float* gW1   = (const float*)d_in[3];
  const float* gb1   = (const float*)d_in[4];
  const float* fW0   = (const float*)d_in[5];
  const float* fb0   = (const float*)d_in[6];
  const float* fW1   = (const float*)d_in[7];
  const float* fb1   = (const float*)d_in[8];
  float* out = (float*)d_out;

  _Float16* W0c  = (_Float16*)d_ws;                     // 65536 fp16 = 128KB
  _Float16* W1c  = W0c + 65536;                         // 128KB
  _Float16* fW0c = W1c + 65536;                         // 128KB
  _Float16* fW1c = fW0c + 65536;                        // 128KB
  float* pooled  = (float*)(fW1c + 65536);              // 1024*256 f32 = 1MB

  const int Bn = in_sizes[0] / 2048;  // 1024

  prep_kernel<<<dim3(256), dim3(256), 0, stream>>>(
      gW0, gW1, fW0, fW1, W0c, W1c, fW0c, fW1c);
  pair_kernel<<<dim3(Bn), dim3(512), 0, stream>>>(state, W0c, gb0, W1c, gb1, pooled);
  fmlp_kernel<<<dim3(Bn / 4), dim3(256), 0, stream>>>(
      pooled, fW0c, fb0, fW1c, fb1, out);
}